// Round 7
// baseline (3251.753 us; speedup 1.0000x reference)
//
#include <hip/hip_runtime.h>
#include <math.h>

#define NN 50000
#define NE 400000
#define NG 512
#define NT 5
#define FI 75
#define FO 15
#define NL 4
#define AVGL 2.1972245773362196f

static inline int cdiv(int a, int b){ return (a+b-1)/b; }

static __device__ __forceinline__ int lowerb(const int* a, int n, int key){
  int lo=0, hi=n;
  while(lo<hi){ int mid=(lo+hi)>>1; if(a[mid]<key) lo=mid+1; else hi=mid; }
  return lo;
}

// ---------------------------------------------------------------- embed
__global__ void k_embed(const int* __restrict__ x, const float* __restrict__ emb,
                        float* __restrict__ h){
  int i = blockIdx.x*256 + threadIdx.x;
  if(i >= NN*FI) return;
  int n = i / FI, f = i - n*FI;
  h[i] = emb[x[n]*FI + f];
}

// ---------------------------------------------------------------- degree count
__global__ void k_count(const int* __restrict__ eidx, int* __restrict__ cnts){
  int e = blockIdx.x*256 + threadIdx.x;
  if(e >= NE) return;
  atomicAdd(&cnts[eidx[NE + e]], 1);
}

// ---------------------------------------------------------------- prefix scan + deg scales
__global__ void k_scan(const int* __restrict__ cnts, int* __restrict__ rowp,
                       float4* __restrict__ dgf){
  __shared__ int s[1024];
  __shared__ int carry_s;
  int tid = threadIdx.x;
  if(tid==0) carry_s = 0;
  __syncthreads();
  for(int base=0; base<NN; base+=1024){
    int i = base + tid;
    int c = (i<NN) ? cnts[i] : 0;
    s[tid] = c; __syncthreads();
    for(int offn=1; offn<1024; offn<<=1){
      int t = (tid>=offn) ? s[tid-offn] : 0;
      __syncthreads();
      s[tid] += t;
      __syncthreads();
    }
    int incl = s[tid];
    int carry = carry_s;
    if(i<NN){
      rowp[i] = carry + incl - c;
      float d  = (float)c;
      float fd = fmaxf(d, 1.f);
      float ld = logf(fd + 1.f);
      dgf[i] = make_float4(d, 1.f/fd, ld/AVGL, AVGL/ld);
    }
    __syncthreads();
    if(tid==0) carry_s += s[1023];
    __syncthreads();
  }
  if(tid==0) rowp[NN] = carry_s;
}

// ---------------------------------------------------------------- CSR scatter
__global__ void k_scatter(const int* __restrict__ eidx, const int* __restrict__ eattr,
                          const int* __restrict__ rowp, int* __restrict__ cur,
                          unsigned int* __restrict__ edata){
  int e = blockIdx.x*256 + threadIdx.x;
  if(e >= NE) return;
  int d = eidx[NE + e];
  int pos = atomicAdd(&cur[d], 1);
  edata[rowp[d] + pos] = (unsigned)eidx[e] | ((unsigned)eattr[e] << 16);
}

// ---------------------------------------------------------------- e_enc table (4 layers x 4 attrs x 75)
__global__ void k_eenc(const float* __restrict__ eemb, const float* __restrict__ encw,
                       const float* __restrict__ encb, float* __restrict__ eenc){
  int idx = blockIdx.x*256 + threadIdx.x;
  if(idx >= NL*4*FI) return;
  int f = idx % FI;
  int a = (idx / FI) % 4;
  int l = idx / (4*FI);
  float s = encb[l*FI + f];
  for(int k=0;k<50;k++) s += eemb[a*50+k] * encw[(l*50+k)*FI + f];
  eenc[(l*4+a)*FI + f] = s;
}

// ---------------------------------------------------------------- c table (folds e_enc path + pre_b)
__global__ void k_ctab(const float* __restrict__ eenc, const float* __restrict__ prew,
                       const float* __restrict__ preb, float* __restrict__ ctab){
  int idx = blockIdx.x*256 + threadIdx.x;
  if(idx >= NL*NT*4*FI) return;
  int f = idx % FI;
  int a = (idx / FI) % 4;
  int t = (idx / (4*FI)) % NT;
  int l = idx / (NT*4*FI);
  float s = preb[(l*NT+t)*FI + f];
  for(int k=0;k<FI;k++)
    s += eenc[(l*4+a)*FI + k] * prew[((l*NT+t)*225 + 150 + k)*FI + f];
  ctab[((l*NT+t)*4 + a)*FI + f] = s;
}

// ---------------------------------------------------------------- B_v (80 x 384) per layer: v = h @ pre_w[75:150]
__global__ void k_bv(const float* __restrict__ prew, float* __restrict__ BV){
  int idx = blockIdx.x*256 + threadIdx.x;
  if(idx >= NL*80*384) return;
  int nn2 = idx % 384;
  int r   = (idx / 384) % 80;
  int l   = idx / (80*384);
  float val = 0.f;
  if(r < FI && nn2 < NT*FI){
    int t = nn2 / FI, f = nn2 % FI;
    val = prew[((l*NT+t)*225 + 75 + r)*FI + f];
  }
  BV[idx] = val;
}

// ---------------------------------------------------------------- B_post (384 x 48) per (layer,tower):
// rows 0..299: post_w agg rows arranged [a|amp|att] x 15 cols; rows 300..374: U = pre_w_u @ (Wa+Wb+Wc)
__global__ void k_bpost(const float* __restrict__ postw, const float* __restrict__ prew,
                        float* __restrict__ BP){
  int idx = blockIdx.x*256 + threadIdx.x;
  if(idx >= NL*NT*384*48) return;
  int j  = idx % 48;
  int k  = (idx / 48) % 384;
  int lt = idx / (384*48);
  int l = lt / NT, t = lt % NT;
  float val = 0.f;
  if(j < 45){
    int jb = j / 15, jo = j % 15;
    int pbase = (l*NT+t)*975;
    if(k < 300){
      val = postw[(pbase + 75 + 300*jb + k)*15 + jo];
    } else if(k < 375){
      int c = k - 300;
      float s = 0.f;
      for(int f=0; f<FI; f++){
        float wsum = postw[(pbase + 75 + 300*jb + f)*15 + jo]
                   + postw[(pbase + 75 + 300*jb + 75 + f)*15 + jo]
                   + postw[(pbase + 75 + 300*jb + 150 + f)*15 + jo];
        s += prew[((l*NT+t)*225 + c)*FI + f] * wsum;
      }
      val = s;
    }
  }
  BP[idx] = val;
}

// ---------------------------------------------------------------- B_x (160 x 80) per layer: [WX@lin_w ; 0 ; lin_w ; 0]
__global__ void k_bx(const float* __restrict__ postw, const float* __restrict__ linw,
                     float* __restrict__ BX){
  int idx = blockIdx.x*256 + threadIdx.x;
  if(idx >= NL*160*80) return;
  int j = idx % 80;
  int r = (idx / 80) % 160;
  int l = idx / (160*80);
  float val = 0.f;
  if(j < FI){
    if(r < FI){
      float s = 0.f;
      for(int m=0; m<FI; m++){
        int t = m / 15, o = m % 15;
        s += postw[((l*NT+t)*975 + r)*15 + o] * linw[(l*FI + m)*FI + j];
      }
      val = s;
    } else if(r >= 80 && r < 155){
      val = linw[(l*FI + (r-80))*FI + j];
    }
  }
  BX[idx] = val;
}

// ---------------------------------------------------------------- generic tiled fp32 GEMM, 64x64x16, 4x4/thread
// MODE 0: V gemm  (A = h, K=75 padded 80) -> C (N,375)
// MODE 1: POST    (A = [aggrel(300) | h*has_edge(75)], K padded 384) -> combine epilogue -> pbuf cols t*15..
// MODE 2: XLIN    (A = [h(75) pad | pbuf(75) pad], K=160) -> hc + lin_b
template<int MODE>
__global__ __launch_bounds__(256)
void k_gemm(const float* __restrict__ A0, const float* __restrict__ A1,
            const float* __restrict__ Bm, const float* __restrict__ ex,
            const float4* __restrict__ dgf, float* __restrict__ C,
            int M, int Kpad, int NB, int Ncols, int tower)
{
  __shared__ float sm[3072];
  float* As = sm;            // [16][68]
  float* Bs = sm + 16*68;    // [16][68]
  const int tid = threadIdx.x;
  const int bm = blockIdx.x*64, bnb = blockIdx.y*64;
  const int tx = tid & 15, ty = tid >> 4;
  const int arow = tid >> 2, akq = (tid & 3) * 4;
  const int bkr = tid >> 4, bn0 = (tid & 15) * 4;
  const int gr_a = bm + arow;
  float hemask = 1.f;
  if(MODE==1) hemask = (gr_a < M && dgf[gr_a].x > 0.f) ? 1.f : 0.f;
  float acc[4][4] = {};
  for(int k0=0; k0<Kpad; k0+=16){
    float av[4];
    #pragma unroll
    for(int j=0;j<4;j++){
      int k = k0 + akq + j;
      float vv = 0.f;
      if(gr_a < M){
        if(MODE==0){
          if(k < 75) vv = A0[gr_a*75 + k];
        } else if(MODE==1){
          if(k < 300) vv = A0[gr_a*300 + k];
          else if(k < 375) vv = A1[gr_a*75 + (k-300)] * hemask;
        } else {
          if(k < 75) vv = A0[gr_a*75 + k];
          else if(k >= 80 && k < 155) vv = A1[gr_a*75 + (k-80)];
        }
      }
      av[j] = vv;
    }
    float4 bv = make_float4(0.f,0.f,0.f,0.f);
    if(bnb + bn0 < NB) bv = *(const float4*)&Bm[(size_t)(k0+bkr)*NB + bnb + bn0];
    __syncthreads();
    #pragma unroll
    for(int j=0;j<4;j++) As[(akq+j)*68 + arow] = av[j];
    *(float4*)&Bs[bkr*68 + bn0] = bv;
    __syncthreads();
    #pragma unroll
    for(int kk=0;kk<16;kk++){
      float4 a4 = *(const float4*)&As[kk*68 + ty*4];
      float4 b4 = *(const float4*)&Bs[kk*68 + tx*4];
      float aa[4] = {a4.x,a4.y,a4.z,a4.w};
      float bb[4] = {b4.x,b4.y,b4.z,b4.w};
      #pragma unroll
      for(int i2=0;i2<4;i2++)
        #pragma unroll
        for(int j2=0;j2<4;j2++)
          acc[i2][j2] += aa[i2]*bb[j2];
    }
  }
  __syncthreads();
  if(MODE==1){
    #pragma unroll
    for(int i2=0;i2<4;i2++){
      #pragma unroll
      for(int j2=0;j2<4;j2++){
        int cc = tx*4 + j2;
        if(cc < 48) sm[(ty*4+i2)*48 + cc] = acc[i2][j2];
      }
    }
    __syncthreads();
    for(int idx=tid; idx<64*15; idx+=256){
      int r = idx / 15, o = idx - r*15;
      int gr = bm + r;
      if(gr < M){
        float4 dg = dgf[gr];
        float val = sm[r*48+o] + dg.z*sm[r*48+15+o] + dg.w*sm[r*48+30+o] + ex[o];
        C[gr*75 + tower*15 + o] = val;
      }
    }
  } else {
    #pragma unroll
    for(int i2=0;i2<4;i2++){
      int gr = bm + ty*4 + i2;
      if(gr >= M) continue;
      #pragma unroll
      for(int j2=0;j2<4;j2++){
        int gc = bnb + tx*4 + j2;
        if(gc < Ncols){
          float val = acc[i2][j2];
          if(MODE==2) val += ex[gc];
          C[(size_t)gr*Ncols + gc] = val;
        }
      }
    }
  }
}

// ---------------------------------------------------------------- per-node aggregation (one wave / node, one tower)
__global__ __launch_bounds__(256)
void k_agg(const int* __restrict__ rowp, const unsigned int* __restrict__ edata,
           const float4* __restrict__ dgf, const float* __restrict__ v,
           const float* __restrict__ ctab_lt, float* __restrict__ agg, int tower)
{
  __shared__ float cs[4*FI];
  int tid = threadIdx.x;
  for(int i=tid; i<4*FI; i+=256) cs[i] = ctab_lt[i];
  __syncthreads();
  int wv = tid >> 6, lane = tid & 63;
  int n = blockIdx.x*4 + wv;
  if(n >= NN) return;
  int beg = rowp[n], end = rowp[n+1];
  float S0=0.f,Q0=0.f,mn0=3.4e38f,mx0=-3.4e38f;
  float S1=0.f,Q1=0.f,mn1=3.4e38f,mx1=-3.4e38f;
  int f0 = lane, f1 = lane + 64;
  bool hv1 = (f1 < FI);
  const float* vt = v + tower*FI;
  for(int e=beg; e<end; e++){
    unsigned ed = edata[e];
    int src = (int)(ed & 0xFFFFu);
    int at  = (int)(ed >> 16);
    const float* vr = vt + (size_t)src*(NT*FI);
    const float* cr = cs + at*FI;
    float w0 = vr[f0] + cr[f0];
    S0 += w0; Q0 += w0*w0; mn0 = fminf(mn0,w0); mx0 = fmaxf(mx0,w0);
    if(hv1){
      float w1 = vr[f1] + cr[f1];
      S1 += w1; Q1 += w1*w1; mn1 = fminf(mn1,w1); mx1 = fmaxf(mx1,w1);
    }
  }
  float4 dg = dgf[n];
  bool he = dg.x > 0.f;
  float* o = agg + (size_t)n*300;
  {
    float mw = S0 * dg.y;
    float sd = sqrtf(fmaxf(Q0*dg.y - mw*mw, 0.f) + 1e-5f);
    o[f0]       = mw;
    o[75+f0]    = he ? mn0 : 0.f;
    o[150+f0]   = he ? mx0 : 0.f;
    o[225+f0]   = sd;
  }
  if(hv1){
    float mw = S1 * dg.y;
    float sd = sqrtf(fmaxf(Q1*dg.y - mw*mw, 0.f) + 1e-5f);
    o[f1]       = mw;
    o[75+f1]    = he ? mn1 : 0.f;
    o[150+f1]   = he ? mx1 : 0.f;
    o[225+f1]   = sd;
  }
}

// ---------------------------------------------------------------- batchnorm stats
__global__ void k_bnstat(const float* __restrict__ hc, float* __restrict__ bn){
  int f = threadIdx.x;
  if(f >= FI) return;
  float s=0.f, q=0.f;
  for(int n=blockIdx.x; n<NN; n+=gridDim.x){
    float xv = hc[(size_t)n*FI + f];
    s += xv; q += xv*xv;
  }
  atomicAdd(&bn[f], s);
  atomicAdd(&bn[FI+f], q);
}

// ---------------------------------------------------------------- batchnorm apply + relu
__global__ void k_bnapply(const float* __restrict__ hc, const float* __restrict__ bn,
                          const float* __restrict__ gam, const float* __restrict__ bet,
                          float* __restrict__ h){
  int i = blockIdx.x*256 + threadIdx.x;
  if(i >= NN*FI) return;
  int f = i % FI;
  float mu  = bn[f] * (1.f/NN);
  float var = bn[FI+f] * (1.f/NN) - mu*mu;
  float y = (hc[i] - mu) / sqrtf(var + 1e-5f) * gam[f] + bet[f];
  h[i] = fmaxf(y, 0.f);
}

// ---------------------------------------------------------------- graph pooling (batch sorted)
__global__ void k_seg(const int* __restrict__ batch, const float* __restrict__ h,
                      float* __restrict__ g){
  __shared__ int slo, shi;
  int b = blockIdx.x, t = threadIdx.x;
  if(t==0) slo = lowerb(batch, NN, b);
  if(t==1) shi = lowerb(batch, NN, b+1);
  __syncthreads();
  if(t >= FI) return;
  float s = 0.f;
  for(int n=slo; n<shi; n++) s += h[(size_t)n*FI + t];
  g[b*FI + t] = s;
}

// ---------------------------------------------------------------- final MLP
__global__ void k_mlp(const float* __restrict__ g,
                      const float* __restrict__ w1, const float* __restrict__ b1,
                      const float* __restrict__ w2, const float* __restrict__ b2,
                      const float* __restrict__ w3, const float* __restrict__ b3,
                      float* __restrict__ out){
  __shared__ float gi[FI], l1[50], l2[25];
  int b = blockIdx.x, t = threadIdx.x;
  if(t < FI) gi[t] = g[b*FI + t];
  __syncthreads();
  if(t < 50){
    float s = b1[t];
    for(int f=0; f<FI; f++) s += gi[f]*w1[f*50 + t];
    l1[t] = fmaxf(s, 0.f);
  }
  __syncthreads();
  if(t < 25){
    float s = b2[t];
    for(int k=0; k<50; k++) s += l1[k]*w2[k*25 + t];
    l2[t] = fmaxf(s, 0.f);
  }
  __syncthreads();
  if(t == 0){
    float s = b3[0];
    for(int k=0; k<25; k++) s += l2[k]*w3[k];
    out[b] = s;
  }
}

// ================================================================ host
extern "C" void kernel_launch(void* const* d_in, const int* in_sizes, int n_in,
                              void* d_out, int out_size, void* d_ws, size_t ws_size,
                              hipStream_t stream)
{
  (void)in_sizes; (void)n_in; (void)out_size; (void)ws_size;
  const int*   X     = (const int*)d_in[0];
  const int*   EIDX  = (const int*)d_in[1];
  const int*   EATTR = (const int*)d_in[2];
  const int*   BATCH = (const int*)d_in[3];
  const float* NEMB  = (const float*)d_in[4];
  const float* EEMB  = (const float*)d_in[5];
  const float* ENCW  = (const float*)d_in[6];
  const float* ENCB  = (const float*)d_in[7];
  const float* PREW  = (const float*)d_in[8];
  const float* PREB  = (const float*)d_in[9];
  const float* POSTW = (const float*)d_in[10];
  const float* POSTB = (const float*)d_in[11];
  const float* LINW  = (const float*)d_in[12];
  const float* LINB  = (const float*)d_in[13];
  const float* GAM   = (const float*)d_in[14];
  const float* BET   = (const float*)d_in[15];
  const float* M1W   = (const float*)d_in[16];
  const float* M1B   = (const float*)d_in[17];
  const float* M2W   = (const float*)d_in[18];
  const float* M2B   = (const float*)d_in[19];
  const float* M3W   = (const float*)d_in[20];
  const float* M3B   = (const float*)d_in[21];
  float* OUT = (float*)d_out;

  char* base = (char*)d_ws; size_t off = 0;
  auto alloc = [&](size_t bytes)->void*{
    off = (off + 255) & ~(size_t)255;
    void* p = base + off; off += bytes; return p;
  };
  float*    h    = (float*)   alloc((size_t)NN*FI*4);
  float*    hc   = (float*)   alloc((size_t)NN*FI*4);
  float*    pbuf = (float*)   alloc((size_t)NN*FI*4);
  float*    v    = (float*)   alloc((size_t)NN*NT*FI*4);
  float*    agg  = (float*)   alloc((size_t)NN*300*4);
  int*      rowp = (int*)     alloc((size_t)(NN+1)*4);
  int*      cnts = (int*)     alloc((size_t)NN*4);
  float4*   dgf  = (float4*)  alloc((size_t)NN*16);
  unsigned* edata= (unsigned*)alloc((size_t)NE*4);
  float*    eenc = (float*)   alloc((size_t)NL*4*FI*4);
  float*    ctab = (float*)   alloc((size_t)NL*NT*4*FI*4);
  float*    BV   = (float*)   alloc((size_t)NL*80*384*4);
  float*    BP   = (float*)   alloc((size_t)NL*NT*384*48*4);
  float*    BX   = (float*)   alloc((size_t)NL*160*80*4);
  float*    bn   = (float*)   alloc((size_t)150*4);
  float*    gbuf = (float*)   alloc((size_t)NG*FI*4);

  hipMemsetAsync(cnts, 0, (size_t)NN*4, stream);
  k_embed  <<<cdiv(NN*FI,256),256,0,stream>>>(X, NEMB, h);
  k_count  <<<cdiv(NE,256),256,0,stream>>>(EIDX, cnts);
  k_scan   <<<1,1024,0,stream>>>(cnts, rowp, dgf);
  hipMemsetAsync(cnts, 0, (size_t)NN*4, stream);
  k_scatter<<<cdiv(NE,256),256,0,stream>>>(EIDX, EATTR, rowp, cnts, edata);
  k_eenc   <<<cdiv(NL*4*FI,256),256,0,stream>>>(EEMB, ENCW, ENCB, eenc);
  k_ctab   <<<cdiv(NL*NT*4*FI,256),256,0,stream>>>(eenc, PREW, PREB, ctab);
  k_bv     <<<cdiv(NL*80*384,256),256,0,stream>>>(PREW, BV);
  k_bpost  <<<cdiv(NL*NT*384*48,256),256,0,stream>>>(POSTW, PREW, BP);
  k_bx     <<<cdiv(NL*160*80,256),256,0,stream>>>(POSTW, LINW, BX);

  for(int l=0; l<NL; l++){
    k_gemm<0><<<dim3(cdiv(NN,64),6),256,0,stream>>>(
        h, nullptr, BV + (size_t)l*80*384, nullptr, dgf, v, NN, 80, 384, 375, 0);
    for(int t=0; t<NT; t++){
      k_agg<<<cdiv(NN,4),256,0,stream>>>(
          rowp, edata, dgf, v, ctab + (size_t)(l*NT+t)*4*FI, agg, t);
      k_gemm<1><<<dim3(cdiv(NN,64),1),256,0,stream>>>(
          agg, h, BP + (size_t)(l*NT+t)*384*48, POSTB + (l*NT+t)*15, dgf, pbuf,
          NN, 384, 48, 75, t);
    }
    k_gemm<2><<<dim3(cdiv(NN,64),2),256,0,stream>>>(
        h, pbuf, BX + (size_t)l*160*80, LINB + l*FI, dgf, hc, NN, 160, 80, 75, 0);
    hipMemsetAsync(bn, 0, 150*4, stream);
    k_bnstat <<<256,128,0,stream>>>(hc, bn);
    k_bnapply<<<cdiv(NN*FI,256),256,0,stream>>>(hc, bn, GAM + l*FI, BET + l*FI, h);
  }
  k_seg<<<NG,128,0,stream>>>(BATCH, h, gbuf);
  k_mlp<<<NG,128,0,stream>>>(gbuf, M1W, M1B, M2W, M2B, M3W, M3B, OUT);
}

// Round 11
// 3083.030 us; speedup vs baseline: 1.0547x; 1.0547x over previous
//
#include <hip/hip_runtime.h>
#include <math.h>

#define NN 50000
#define NE 400000
#define NG 512
#define NT 5
#define FI 75
#define FO 15
#define NL 4
#define AVGL 2.1972245773362196f
#define SCAN_NB 196   // cdiv(NN,256)

static inline int cdiv(int a, int b){ return (a+b-1)/b; }

static __device__ __forceinline__ float bf2f(unsigned short u){
  union{unsigned i; float f;} c; c.i = ((unsigned)u)<<16; return c.f;
}
static __device__ __forceinline__ unsigned short f2bf(float x){
  union{float f; unsigned i;} c; c.f = x;
  unsigned r = (c.i + 0x7FFFu + ((c.i>>16)&1u)) >> 16;
  return (unsigned short)r;
}

static __device__ __forceinline__ int lowerb(const int* a, int n, int key){
  int lo=0, hi=n;
  while(lo<hi){ int mid=(lo+hi)>>1; if(a[mid]<key) lo=mid+1; else hi=mid; }
  return lo;
}

// ---------------------------------------------------------------- embed
__global__ void k_embed(const int* __restrict__ x, const float* __restrict__ emb,
                        float* __restrict__ h){
  int i = blockIdx.x*256 + threadIdx.x;
  if(i >= NN*FI) return;
  int n = i / FI, f = i - n*FI;
  h[i] = emb[x[n]*FI + f];
}

// ---------------------------------------------------------------- degree count
__global__ void k_count(const int* __restrict__ eidx, int* __restrict__ cnts){
  int e = blockIdx.x*256 + threadIdx.x;
  if(e >= NE) return;
  atomicAdd(&cnts[eidx[NE + e]], 1);
}

// ---------------------------------------------------------------- parallel scan, stage 1: per-block scan
__global__ void k_bscan(const int* __restrict__ cnts, int* __restrict__ rowp,
                        int* __restrict__ bsum){
  __shared__ int s[256];
  int t = threadIdx.x, i = blockIdx.x*256 + t;
  int c = (i<NN) ? cnts[i] : 0;
  s[t] = c; __syncthreads();
  for(int o=1;o<256;o<<=1){
    int x = (t>=o) ? s[t-o] : 0; __syncthreads();
    s[t] += x; __syncthreads();
  }
  if(i<NN) rowp[i] = s[t] - c;          // local exclusive
  if(t==255) bsum[blockIdx.x] = s[255]; // block total
}

// ---------------------------------------------------------------- stage 2: scan block sums (1 block)
__global__ void k_bsums(const int* __restrict__ bsum, int* __restrict__ boff,
                        int* __restrict__ rowp){
  __shared__ int s[256];
  int t = threadIdx.x;
  int v = (t<SCAN_NB) ? bsum[t] : 0;
  s[t] = v; __syncthreads();
  for(int o=1;o<256;o<<=1){
    int x = (t>=o) ? s[t-o] : 0; __syncthreads();
    s[t] += x; __syncthreads();
  }
  if(t<SCAN_NB) boff[t] = s[t] - v;     // exclusive
  if(t==255) rowp[NN] = s[255];         // grand total
}

// ---------------------------------------------------------------- stage 3: add-back + degree scales
__global__ void k_badd(const int* __restrict__ boff, const int* __restrict__ cnts,
                       int* __restrict__ rowp, float4* __restrict__ dgf){
  int i = blockIdx.x*256 + threadIdx.x;
  if(i >= NN) return;
  rowp[i] += boff[i>>8];
  int c = cnts[i];
  float d  = (float)c;
  float fd = fmaxf(d, 1.f);
  float ld = logf(fd + 1.f);
  dgf[i] = make_float4(d, 1.f/fd, ld/AVGL, AVGL/ld);
}

// ---------------------------------------------------------------- CSR scatter
__global__ void k_scatter(const int* __restrict__ eidx, const int* __restrict__ eattr,
                          const int* __restrict__ rowp, int* __restrict__ cur,
                          unsigned int* __restrict__ edata){
  int e = blockIdx.x*256 + threadIdx.x;
  if(e >= NE) return;
  int d = eidx[NE + e];
  int pos = atomicAdd(&cur[d], 1);
  edata[rowp[d] + pos] = (unsigned)eidx[e] | ((unsigned)eattr[e] << 16);
}

// ---------------------------------------------------------------- e_enc table (4 layers x 4 attrs x 75)
__global__ void k_eenc(const float* __restrict__ eemb, const float* __restrict__ encw,
                       const float* __restrict__ encb, float* __restrict__ eenc){
  int idx = blockIdx.x*256 + threadIdx.x;
  if(idx >= NL*4*FI) return;
  int f = idx % FI;
  int a = (idx / FI) % 4;
  int l = idx / (4*FI);
  float s = encb[l*FI + f];
  for(int k=0;k<50;k++) s += eemb[a*50+k] * encw[(l*50+k)*FI + f];
  eenc[(l*4+a)*FI + f] = s;
}

// ---------------------------------------------------------------- c table (folds e_enc path + pre_b)
__global__ void k_ctab(const float* __restrict__ eenc, const float* __restrict__ prew,
                       const float* __restrict__ preb, float* __restrict__ ctab){
  int idx = blockIdx.x*256 + threadIdx.x;
  if(idx >= NL*NT*4*FI) return;
  int f = idx % FI;
  int a = (idx / FI) % 4;
  int t = (idx / (4*FI)) % NT;
  int l = idx / (NT*4*FI);
  float s = preb[(l*NT+t)*FI + f];
  for(int k=0;k<FI;k++)
    s += eenc[(l*4+a)*FI + k] * prew[((l*NT+t)*225 + 150 + k)*FI + f];
  ctab[((l*NT+t)*4 + a)*FI + f] = s;
}

// ---------------------------------------------------------------- B_v (80 x 400) per layer (padded, bf16-v target)
__global__ void k_bv(const float* __restrict__ prew, float* __restrict__ BV){
  int idx = blockIdx.x*256 + threadIdx.x;
  if(idx >= NL*80*400) return;
  int nn2 = idx % 400;
  int r   = (idx / 400) % 80;
  int l   = idx / (80*400);
  int t = nn2 / 80, f = nn2 % 80;
  float val = 0.f;
  if(r < FI && f < FI)
    val = prew[((l*NT+t)*225 + 75 + r)*FI + f];
  BV[idx] = val;
}

// ---------------------------------------------------------------- B_post (400 x 48) per (layer,tower)
// k<320: agg stat s=k/80, feature f=k%80 (pad f>=75 -> 0); k in [320,400): U-fold rows
__global__ void k_bpost(const float* __restrict__ postw, const float* __restrict__ prew,
                        float* __restrict__ BP){
  int idx = blockIdx.x*256 + threadIdx.x;
  if(idx >= NL*NT*400*48) return;
  int j  = idx % 48;
  int k  = (idx / 48) % 400;
  int lt = idx / (400*48);
  int l = lt / NT, t = lt % NT;
  float val = 0.f;
  if(j < 45){
    int jb = j / 15, jo = j % 15;
    int pbase = (l*NT+t)*975;
    if(k < 320){
      int s = k / 80, f = k % 80;
      if(f < FI)
        val = postw[(pbase + 75 + 300*jb + s*75 + f)*15 + jo];
    } else {
      int c = k - 320;
      if(c < FI){
        float s2 = 0.f;
        for(int f=0; f<FI; f++){
          float wsum = postw[(pbase + 75 + 300*jb + f)*15 + jo]
                     + postw[(pbase + 75 + 300*jb + 75 + f)*15 + jo]
                     + postw[(pbase + 75 + 300*jb + 150 + f)*15 + jo];
          s2 += prew[((l*NT+t)*225 + c)*FI + f] * wsum;
        }
        val = s2;
      }
    }
  }
  BP[idx] = val;
}

// ---------------------------------------------------------------- B_x (160 x 80) per layer: [WX@lin_w ; 0 ; lin_w ; 0]
__global__ void k_bx(const float* __restrict__ postw, const float* __restrict__ linw,
                     float* __restrict__ BX){
  int idx = blockIdx.x*256 + threadIdx.x;
  if(idx >= NL*160*80) return;
  int j = idx % 80;
  int r = (idx / 80) % 160;
  int l = idx / (160*80);
  float val = 0.f;
  if(j < FI){
    if(r < FI){
      float s = 0.f;
      for(int m=0; m<FI; m++){
        int t = m / 15, o = m % 15;
        s += postw[((l*NT+t)*975 + r)*15 + o] * linw[(l*FI + m)*FI + j];
      }
      val = s;
    } else if(r >= 80 && r < 155){
      val = linw[(l*FI + (r-80))*FI + j];
    }
  }
  BX[idx] = val;
}

// ---------------------------------------------------------------- generic tiled fp32 GEMM, 64x64x16, 4x4/thread
// MODE 0: V gemm  (A=h fp32, K=80pad) -> C bf16 (N,400)
// MODE 1: POST    (A=[agg bf16(320) | h fp32*hemask(80pad)], K=400) -> epilogue -> pbuf fp32 cols t*15..
// MODE 2: XLIN    (A=[h(75)pad | pbuf(75)pad], K=160) -> hc fp32 + lin_b
template<int MODE>
__global__ __launch_bounds__(256)
void k_gemm(const void* __restrict__ A0, const float* __restrict__ A1,
            const float* __restrict__ Bm, const float* __restrict__ ex,
            const float4* __restrict__ dgf, void* __restrict__ C,
            int M, int Kpad, int NB, int Ncols, int tower)
{
  __shared__ float sm[3072];
  float* As = sm;            // [16][68] transposed
  float* Bs = sm + 16*68;    // [16][68]
  const int tid = threadIdx.x;
  const int bm = blockIdx.x*64, bnb = blockIdx.y*64;
  const int tx = tid & 15, ty = tid >> 4;
  const int arow = tid >> 2, akq = (tid & 3) * 4;
  const int bkr = tid >> 4, bn0 = (tid & 15) * 4;
  const int gr_a = bm + arow;
  float hemask = 1.f;
  if(MODE==1) hemask = (gr_a < M && dgf[gr_a].x > 0.f) ? 1.f : 0.f;
  float acc[4][4] = {};
  for(int k0=0; k0<Kpad; k0+=16){
    float av[4];
    if(MODE==1){
      int k = k0 + akq;
      if(k < 320){
        if(gr_a < M){
          const unsigned short* Ag = (const unsigned short*)A0;
          uint2 p = *(const uint2*)&Ag[(size_t)gr_a*320 + k];
          av[0] = bf2f((unsigned short)(p.x & 0xFFFFu));
          av[1] = bf2f((unsigned short)(p.x >> 16));
          av[2] = bf2f((unsigned short)(p.y & 0xFFFFu));
          av[3] = bf2f((unsigned short)(p.y >> 16));
        } else { av[0]=av[1]=av[2]=av[3]=0.f; }
      } else {
        #pragma unroll
        for(int j=0;j<4;j++){
          int f = k + j - 320;
          av[j] = (gr_a < M && f < FI) ? A1[gr_a*FI + f] * hemask : 0.f;
        }
      }
    } else if(MODE==0){
      const float* Ah = (const float*)A0;
      #pragma unroll
      for(int j=0;j<4;j++){
        int k = k0 + akq + j;
        av[j] = (gr_a < M && k < FI) ? Ah[gr_a*FI + k] : 0.f;
      }
    } else {
      const float* Ah = (const float*)A0;
      #pragma unroll
      for(int j=0;j<4;j++){
        int k = k0 + akq + j;
        float vv = 0.f;
        if(gr_a < M){
          if(k < 75) vv = Ah[gr_a*75 + k];
          else if(k >= 80 && k < 155) vv = A1[gr_a*75 + (k-80)];
        }
        av[j] = vv;
      }
    }
    float4 bv = make_float4(0.f,0.f,0.f,0.f);
    if(bnb + bn0 < NB) bv = *(const float4*)&Bm[(size_t)(k0+bkr)*NB + bnb + bn0];
    __syncthreads();
    #pragma unroll
    for(int j=0;j<4;j++) As[(akq+j)*68 + arow] = av[j];
    *(float4*)&Bs[bkr*68 + bn0] = bv;
    __syncthreads();
    #pragma unroll
    for(int kk=0;kk<16;kk++){
      float4 a4 = *(const float4*)&As[kk*68 + ty*4];
      float4 b4 = *(const float4*)&Bs[kk*68 + tx*4];
      float aa[4] = {a4.x,a4.y,a4.z,a4.w};
      float bb[4] = {b4.x,b4.y,b4.z,b4.w};
      #pragma unroll
      for(int i2=0;i2<4;i2++)
        #pragma unroll
        for(int j2=0;j2<4;j2++)
          acc[i2][j2] += aa[i2]*bb[j2];
    }
  }
  __syncthreads();
  if(MODE==1){
    #pragma unroll
    for(int i2=0;i2<4;i2++){
      #pragma unroll
      for(int j2=0;j2<4;j2++){
        int cc = tx*4 + j2;
        if(cc < 48) sm[(ty*4+i2)*48 + cc] = acc[i2][j2];
      }
    }
    __syncthreads();
    float* Cf = (float*)C;
    for(int idx=tid; idx<64*15; idx+=256){
      int r = idx / 15, o = idx - r*15;
      int gr = bm + r;
      if(gr < M){
        float4 dg = dgf[gr];
        float val = sm[r*48+o] + dg.z*sm[r*48+15+o] + dg.w*sm[r*48+30+o] + ex[o];
        Cf[(size_t)gr*75 + tower*15 + o] = val;
      }
    }
  } else if(MODE==0){
    unsigned short* Cv = (unsigned short*)C;
    #pragma unroll
    for(int i2=0;i2<4;i2++){
      int gr = bm + ty*4 + i2;
      if(gr >= M) continue;
      int gc0 = bnb + tx*4;
      if(gc0 < Ncols){
        unsigned lo = (unsigned)f2bf(acc[i2][0]) | ((unsigned)f2bf(acc[i2][1])<<16);
        unsigned hi = (unsigned)f2bf(acc[i2][2]) | ((unsigned)f2bf(acc[i2][3])<<16);
        *(uint2*)&Cv[(size_t)gr*400 + gc0] = make_uint2(lo,hi);
      }
    }
  } else {
    float* Cf = (float*)C;
    #pragma unroll
    for(int i2=0;i2<4;i2++){
      int gr = bm + ty*4 + i2;
      if(gr >= M) continue;
      #pragma unroll
      for(int j2=0;j2<4;j2++){
        int gc = bnb + tx*4 + j2;
        if(gc < Ncols){
          Cf[(size_t)gr*Ncols + gc] = acc[i2][j2] + ex[gc];
        }
      }
    }
  }
}

// ---------------------------------------------------------------- per-node aggregation (1 wave/node), bf16 v -> bf16 agg
__global__ __launch_bounds__(256)
void k_agg(const int* __restrict__ rowp, const unsigned int* __restrict__ edata,
           const float4* __restrict__ dgf, const unsigned short* __restrict__ v,
           const float* __restrict__ ctab_lt, unsigned short* __restrict__ agg, int tower)
{
  __shared__ float cs[4*80];
  int tid = threadIdx.x;
  for(int i=tid; i<320; i+=256){
    int a = i/80, f = i%80;
    cs[i] = (f < FI) ? ctab_lt[a*FI + f] : 0.f;
  }
  __syncthreads();
  int wv = tid >> 6, lane = tid & 63;
  int n = blockIdx.x*4 + wv;
  if(n >= NN) return;
  int beg = rowp[n], end = rowp[n+1];
  bool act = lane < 40;
  int f0 = 2*lane, f1 = f0 + 1;
  float s0=0.f,s1=0.f,q0=0.f,q1=0.f;
  float mn0=3.4e38f,mn1=3.4e38f,mx0=-3.4e38f,mx1=-3.4e38f;
  const size_t tb = (size_t)tower*80;
  for(int e=beg; e<end; e++){
    unsigned ed = edata[e];
    int src = (int)(ed & 0xFFFFu);
    int at  = (int)(ed >> 16);
    if(act){
      unsigned pv = *(const unsigned*)&v[(size_t)src*400 + tb + f0];
      float w0 = bf2f((unsigned short)(pv & 0xFFFFu)) + cs[at*80 + f0];
      float w1 = bf2f((unsigned short)(pv >> 16))     + cs[at*80 + f1];
      s0 += w0; q0 += w0*w0; mn0 = fminf(mn0,w0); mx0 = fmaxf(mx0,w0);
      s1 += w1; q1 += w1*w1; mn1 = fminf(mn1,w1); mx1 = fmaxf(mx1,w1);
    }
  }
  if(!act) return;
  float4 dg = dgf[n];
  bool he = dg.x > 0.f;
  float m0 = s0*dg.y, m1 = s1*dg.y;
  float sd0 = sqrtf(fmaxf(q0*dg.y - m0*m0, 0.f) + 1e-5f);
  float sd1 = sqrtf(fmaxf(q1*dg.y - m1*m1, 0.f) + 1e-5f);
  float vmn0 = he ? mn0 : 0.f, vmn1 = he ? mn1 : 0.f;
  float vmx0 = he ? mx0 : 0.f, vmx1 = he ? mx1 : 0.f;
  if(f0 >= FI){ m0=0.f; sd0=0.f; vmn0=0.f; vmx0=0.f; }
  if(f1 >= FI){ m1=0.f; sd1=0.f; vmn1=0.f; vmx1=0.f; }
  unsigned short* o = agg + (size_t)n*320;
  *(unsigned*)&o[0*80+f0] = (unsigned)f2bf(m0)   | ((unsigned)f2bf(m1)<<16);
  *(unsigned*)&o[1*80+f0] = (unsigned)f2bf(vmn0) | ((unsigned)f2bf(vmn1)<<16);
  *(unsigned*)&o[2*80+f0] = (unsigned)f2bf(vmx0) | ((unsigned)f2bf(vmx1)<<16);
  *(unsigned*)&o[3*80+f0] = (unsigned)f2bf(sd0)  | ((unsigned)f2bf(sd1)<<16);
}

// ---------------------------------------------------------------- batchnorm stats
__global__ void k_bnstat(const float* __restrict__ hc, float* __restrict__ bn){
  int f = threadIdx.x;
  if(f >= FI) return;
  float s=0.f, q=0.f;
  for(int n=blockIdx.x; n<NN; n+=gridDim.x){
    float xv = hc[(size_t)n*FI + f];
    s += xv; q += xv*xv;
  }
  atomicAdd(&bn[f], s);
  atomicAdd(&bn[FI+f], q);
}

// ---------------------------------------------------------------- batchnorm apply + relu
__global__ void k_bnapply(const float* __restrict__ hc, const float* __restrict__ bn,
                          const float* __restrict__ gam, const float* __restrict__ bet,
                          float* __restrict__ h){
  int i = blockIdx.x*256 + threadIdx.x;
  if(i >= NN*FI) return;
  int f = i % FI;
  float mu  = bn[f] * (1.f/NN);
  float var = bn[FI+f] * (1.f/NN) - mu*mu;
  float y = (hc[i] - mu) / sqrtf(var + 1e-5f) * gam[f] + bet[f];
  h[i] = fmaxf(y, 0.f);
}

// ---------------------------------------------------------------- graph pooling (batch sorted)
__global__ void k_seg(const int* __restrict__ batch, const float* __restrict__ h,
                      float* __restrict__ g){
  __shared__ int slo, shi;
  int b = blockIdx.x, t = threadIdx.x;
  if(t==0) slo = lowerb(batch, NN, b);
  if(t==1) shi = lowerb(batch, NN, b+1);
  __syncthreads();
  if(t >= FI) return;
  float s = 0.f;
  for(int n=slo; n<shi; n++) s += h[(size_t)n*FI + t];
  g[b*FI + t] = s;
}

// ---------------------------------------------------------------- final MLP
__global__ void k_mlp(const float* __restrict__ g,
                      const float* __restrict__ w1, const float* __restrict__ b1,
                      const float* __restrict__ w2, const float* __restrict__ b2,
                      const float* __restrict__ w3, const float* __restrict__ b3,
                      float* __restrict__ out){
  __shared__ float gi[FI], l1[50], l2[25];
  int b = blockIdx.x, t = threadIdx.x;
  if(t < FI) gi[t] = g[b*FI + t];
  __syncthreads();
  if(t < 50){
    float s = b1[t];
    for(int f=0; f<FI; f++) s += gi[f]*w1[f*50 + t];
    l1[t] = fmaxf(s, 0.f);
  }
  __syncthreads();
  if(t < 25){
    float s = b2[t];
    for(int k=0; k<50; k++) s += l1[k]*w2[k*25 + t];
    l2[t] = fmaxf(s, 0.f);
  }
  __syncthreads();
  if(t == 0){
    float s = b3[0];
    for(int k=0; k<25; k++) s += l2[k]*w3[k];
    out[b] = s;
  }
}

// ================================================================ host
extern "C" void kernel_launch(void* const* d_in, const int* in_sizes, int n_in,
                              void* d_out, int out_size, void* d_ws, size_t ws_size,
                              hipStream_t stream)
{
  (void)in_sizes; (void)n_in; (void)out_size; (void)ws_size;
  const int*   X     = (const int*)d_in[0];
  const int*   EIDX  = (const int*)d_in[1];
  const int*   EATTR = (const int*)d_in[2];
  const int*   BATCH = (const int*)d_in[3];
  const float* NEMB  = (const float*)d_in[4];
  const float* EEMB  = (const float*)d_in[5];
  const float* ENCW  = (const float*)d_in[6];
  const float* ENCB  = (const float*)d_in[7];
  const float* PREW  = (const float*)d_in[8];
  const float* PREB  = (const float*)d_in[9];
  const float* POSTW = (const float*)d_in[10];
  const float* POSTB = (const float*)d_in[11];
  const float* LINW  = (const float*)d_in[12];
  const float* LINB  = (const float*)d_in[13];
  const float* GAM   = (const float*)d_in[14];
  const float* BET   = (const float*)d_in[15];
  const float* M1W   = (const float*)d_in[16];
  const float* M1B   = (const float*)d_in[17];
  const float* M2W   = (const float*)d_in[18];
  const float* M2B   = (const float*)d_in[19];
  const float* M3W   = (const float*)d_in[20];
  const float* M3B   = (const float*)d_in[21];
  float* OUT = (float*)d_out;

  char* base = (char*)d_ws; size_t off = 0;
  auto alloc = [&](size_t bytes)->void*{
    off = (off + 255) & ~(size_t)255;
    void* p = base + off; off += bytes; return p;
  };
  float*          h    = (float*)          alloc((size_t)NN*FI*4);
  float*          hc   = (float*)          alloc((size_t)NN*FI*4);
  float*          pbuf = (float*)          alloc((size_t)NN*FI*4);
  unsigned short* v    = (unsigned short*) alloc((size_t)NN*400*2);
  unsigned short* agg  = (unsigned short*) alloc((size_t)NN*320*2);
  int*            rowp = (int*)            alloc((size_t)(NN+1)*4);
  int*            cnts = (int*)            alloc((size_t)NN*4);
  int*            bsum = (int*)            alloc((size_t)256*4);
  int*            boff = (int*)            alloc((size_t)256*4);
  float4*         dgf  = (float4*)         alloc((size_t)NN*16);
  unsigned*       edata= (unsigned*)       alloc((size_t)NE*4);
  float*          eenc = (float*)          alloc((size_t)NL*4*FI*4);
  float*          ctab = (float*)          alloc((size_t)NL*NT*4*FI*4);
  float*          BV   = (float*)          alloc((size_t)NL*80*400*4);
  float*          BP   = (float*)          alloc((size_t)NL*NT*400*48*4);
  float*          BX   = (float*)          alloc((size_t)NL*160*80*4);
  float*          bn   = (float*)          alloc((size_t)150*4);
  float*          gbuf = (float*)          alloc((size_t)NG*FI*4);

  hipMemsetAsync(cnts, 0, (size_t)NN*4, stream);
  k_embed  <<<cdiv(NN*FI,256),256,0,stream>>>(X, NEMB, h);
  k_count  <<<cdiv(NE,256),256,0,stream>>>(EIDX, cnts);
  k_bscan  <<<SCAN_NB,256,0,stream>>>(cnts, rowp, bsum);
  k_bsums  <<<1,256,0,stream>>>(bsum, boff, rowp);
  k_badd   <<<SCAN_NB,256,0,stream>>>(boff, cnts, rowp, dgf);
  hipMemsetAsync(cnts, 0, (size_t)NN*4, stream);
  k_scatter<<<cdiv(NE,256),256,0,stream>>>(EIDX, EATTR, rowp, cnts, edata);
  k_eenc   <<<cdiv(NL*4*FI,256),256,0,stream>>>(EEMB, ENCW, ENCB, eenc);
  k_ctab   <<<cdiv(NL*NT*4*FI,256),256,0,stream>>>(eenc, PREW, PREB, ctab);
  k_bv     <<<cdiv(NL*80*400,256),256,0,stream>>>(PREW, BV);
  k_bpost  <<<cdiv(NL*NT*400*48,256),256,0,stream>>>(POSTW, PREW, BP);
  k_bx     <<<cdiv(NL*160*80,256),256,0,stream>>>(POSTW, LINW, BX);

  for(int l=0; l<NL; l++){
    k_gemm<0><<<dim3(cdiv(NN,64),7),256,0,stream>>>(
        h, nullptr, BV + (size_t)l*80*400, nullptr, dgf, v, NN, 80, 400, 400, 0);
    for(int t=0; t<NT; t++){
      k_agg<<<cdiv(NN,4),256,0,stream>>>(
          rowp, edata, dgf, v, ctab + (size_t)(l*NT+t)*4*FI, agg, t);
      k_gemm<1><<<dim3(cdiv(NN,64),1),256,0,stream>>>(
          agg, h, BP + (size_t)(l*NT+t)*400*48, POSTB + (l*NT+t)*15, dgf, pbuf,
          NN, 400, 48, 75, t);
    }
    k_gemm<2><<<dim3(cdiv(NN,64),2),256,0,stream>>>(
        h, pbuf, BX + (size_t)l*160*80, LINB + l*FI, dgf, hc, NN, 160, 80, 75, 0);
    hipMemsetAsync(bn, 0, 150*4, stream);
    k_bnstat <<<256,128,0,stream>>>(hc, bn);
    k_bnapply<<<cdiv(NN*FI,256),256,0,stream>>>(hc, bn, GAM + l*FI, BET + l*FI, h);
  }
  k_seg<<<NG,128,0,stream>>>(BATCH, h, gbuf);
  k_mlp<<<NG,128,0,stream>>>(gbuf, M1W, M1B, M2W, M2B, M3W, M3B, OUT);
}

// Round 13
// 1964.657 us; speedup vs baseline: 1.6551x; 1.5692x over previous
//
#include <hip/hip_runtime.h>
#include <math.h>

#define NN 50000
#define NE 400000
#define NG 512
#define NT 5
#define FI 75
#define FO 15
#define NL 4
#define AVGL 2.1972245773362196f
#define SCAN_NB 196   // cdiv(NN,256)

static inline int cdiv(int a, int b){ return (a+b-1)/b; }

static __device__ __forceinline__ float bf2f(unsigned short u){
  union{unsigned i; float f;} c; c.i = ((unsigned)u)<<16; return c.f;
}
static __device__ __forceinline__ unsigned short f2bf(float x){
  union{float f; unsigned i;} c; c.f = x;
  unsigned r = (c.i + 0x7FFFu + ((c.i>>16)&1u)) >> 16;
  return (unsigned short)r;
}
static __device__ __forceinline__ unsigned pk2(float a, float b){
  return (unsigned)f2bf(a) | ((unsigned)f2bf(b)<<16);
}

static __device__ __forceinline__ int lowerb(const int* a, int n, int key){
  int lo=0, hi=n;
  while(lo<hi){ int mid=(lo+hi)>>1; if(a[mid]<key) lo=mid+1; else hi=mid; }
  return lo;
}

// ---------------------------------------------------------------- embed
__global__ void k_embed(const int* __restrict__ x, const float* __restrict__ emb,
                        float* __restrict__ h){
  int i = blockIdx.x*256 + threadIdx.x;
  if(i >= NN*FI) return;
  int n = i / FI, f = i - n*FI;
  h[i] = emb[x[n]*FI + f];
}

// ---------------------------------------------------------------- degree count
__global__ void k_count(const int* __restrict__ eidx, int* __restrict__ cnts){
  int e = blockIdx.x*256 + threadIdx.x;
  if(e >= NE) return;
  atomicAdd(&cnts[eidx[NE + e]], 1);
}

// ---------------------------------------------------------------- parallel scan, stage 1
__global__ void k_bscan(const int* __restrict__ cnts, int* __restrict__ rowp,
                        int* __restrict__ bsum){
  __shared__ int s[256];
  int t = threadIdx.x, i = blockIdx.x*256 + t;
  int c = (i<NN) ? cnts[i] : 0;
  s[t] = c; __syncthreads();
  for(int o=1;o<256;o<<=1){
    int x = (t>=o) ? s[t-o] : 0; __syncthreads();
    s[t] += x; __syncthreads();
  }
  if(i<NN) rowp[i] = s[t] - c;
  if(t==255) bsum[blockIdx.x] = s[255];
}

// ---------------------------------------------------------------- stage 2
__global__ void k_bsums(const int* __restrict__ bsum, int* __restrict__ boff,
                        int* __restrict__ rowp){
  __shared__ int s[256];
  int t = threadIdx.x;
  int v = (t<SCAN_NB) ? bsum[t] : 0;
  s[t] = v; __syncthreads();
  for(int o=1;o<256;o<<=1){
    int x = (t>=o) ? s[t-o] : 0; __syncthreads();
    s[t] += x; __syncthreads();
  }
  if(t<SCAN_NB) boff[t] = s[t] - v;
  if(t==255) rowp[NN] = s[255];
}

// ---------------------------------------------------------------- stage 3
__global__ void k_badd(const int* __restrict__ boff, const int* __restrict__ cnts,
                       int* __restrict__ rowp, float4* __restrict__ dgf){
  int i = blockIdx.x*256 + threadIdx.x;
  if(i >= NN) return;
  rowp[i] += boff[i>>8];
  int c = cnts[i];
  float d  = (float)c;
  float fd = fmaxf(d, 1.f);
  float ld = logf(fd + 1.f);
  dgf[i] = make_float4(d, 1.f/fd, ld/AVGL, AVGL/ld);
}

// ---------------------------------------------------------------- CSR scatter
__global__ void k_scatter(const int* __restrict__ eidx, const int* __restrict__ eattr,
                          const int* __restrict__ rowp, int* __restrict__ cur,
                          unsigned int* __restrict__ edata){
  int e = blockIdx.x*256 + threadIdx.x;
  if(e >= NE) return;
  int d = eidx[NE + e];
  int pos = atomicAdd(&cur[d], 1);
  edata[rowp[d] + pos] = (unsigned)eidx[e] | ((unsigned)eattr[e] << 16);
}

// ---------------------------------------------------------------- e_enc table
__global__ void k_eenc(const float* __restrict__ eemb, const float* __restrict__ encw,
                       const float* __restrict__ encb, float* __restrict__ eenc){
  int idx = blockIdx.x*256 + threadIdx.x;
  if(idx >= NL*4*FI) return;
  int f = idx % FI;
  int a = (idx / FI) % 4;
  int l = idx / (4*FI);
  float s = encb[l*FI + f];
  for(int k=0;k<50;k++) s += eemb[a*50+k] * encw[(l*50+k)*FI + f];
  eenc[(l*4+a)*FI + f] = s;
}

// ---------------------------------------------------------------- c table
__global__ void k_ctab(const float* __restrict__ eenc, const float* __restrict__ prew,
                       const float* __restrict__ preb, float* __restrict__ ctab){
  int idx = blockIdx.x*256 + threadIdx.x;
  if(idx >= NL*NT*4*FI) return;
  int f = idx % FI;
  int a = (idx / FI) % 4;
  int t = (idx / (4*FI)) % NT;
  int l = idx / (NT*4*FI);
  float s = preb[(l*NT+t)*FI + f];
  for(int k=0;k<FI;k++)
    s += eenc[(l*4+a)*FI + k] * prew[((l*NT+t)*225 + 150 + k)*FI + f];
  ctab[((l*NT+t)*4 + a)*FI + f] = s;
}

// ---------------------------------------------------------------- B_v (80 x 400) per layer
__global__ void k_bv(const float* __restrict__ prew, float* __restrict__ BV){
  int idx = blockIdx.x*256 + threadIdx.x;
  if(idx >= NL*80*400) return;
  int nn2 = idx % 400;
  int r   = (idx / 400) % 80;
  int l   = idx / (80*400);
  int t = nn2 / 80, f = nn2 % 80;
  float val = 0.f;
  if(r < FI && f < FI)
    val = prew[((l*NT+t)*225 + 75 + r)*FI + f];
  BV[idx] = val;
}

// ---------------------------------------------------------------- B_post (400 x 48) per (layer,tower)
__global__ void k_bpost(const float* __restrict__ postw, const float* __restrict__ prew,
                        float* __restrict__ BP){
  int idx = blockIdx.x*256 + threadIdx.x;
  if(idx >= NL*NT*400*48) return;
  int j  = idx % 48;
  int k  = (idx / 48) % 400;
  int lt = idx / (400*48);
  int l = lt / NT, t = lt % NT;
  float val = 0.f;
  if(j < 45){
    int jb = j / 15, jo = j % 15;
    int pbase = (l*NT+t)*975;
    if(k < 320){
      int s = k / 80, f = k % 80;
      if(f < FI)
        val = postw[(pbase + 75 + 300*jb + s*75 + f)*15 + jo];
    } else {
      int c = k - 320;
      if(c < FI){
        float s2 = 0.f;
        for(int f=0; f<FI; f++){
          float wsum = postw[(pbase + 75 + 300*jb + f)*15 + jo]
                     + postw[(pbase + 75 + 300*jb + 75 + f)*15 + jo]
                     + postw[(pbase + 75 + 300*jb + 150 + f)*15 + jo];
          s2 += prew[((l*NT+t)*225 + c)*FI + f] * wsum;
        }
        val = s2;
      }
    }
  }
  BP[idx] = val;
}

// ---------------------------------------------------------------- B_x (160 x 80) per layer
__global__ void k_bx(const float* __restrict__ postw, const float* __restrict__ linw,
                     float* __restrict__ BX){
  int idx = blockIdx.x*256 + threadIdx.x;
  if(idx >= NL*160*80) return;
  int j = idx % 80;
  int r = (idx / 80) % 160;
  int l = idx / (160*80);
  float val = 0.f;
  if(j < FI){
    if(r < FI){
      float s = 0.f;
      for(int m=0; m<FI; m++){
        int t = m / 15, o = m % 15;
        s += postw[((l*NT+t)*975 + r)*15 + o] * linw[(l*FI + m)*FI + j];
      }
      val = s;
    } else if(r >= 80 && r < 155){
      val = linw[(l*FI + (r-80))*FI + j];
    }
  }
  BX[idx] = val;
}

// ---------------------------------------------------------------- tiled fp32 GEMM, 64-row blocks
// MODE 0: V gemm  (A=h fp32, K=80pad, grid.y = N-tile) -> C bf16 (N,400)
// MODE 1: POST    (grid.y = tower; A=[agg bf16 plane t (320) | h fp32*hemask(80pad)], K=400,
//                  N=48 with 4x3 thread tile) -> epilogue -> pbuf fp32 cols t*15..
// MODE 2: XLIN    (A=[h(75)pad | pbuf(75)pad], K=160) -> hc fp32 + lin_b
template<int MODE>
__global__ __launch_bounds__(256)
void k_gemm(const void* __restrict__ A0, const float* __restrict__ A1,
            const float* __restrict__ Bm, const float* __restrict__ ex,
            const float4* __restrict__ dgf, void* __restrict__ C,
            int M, int Kpad, int NB, int Ncols, int tower)
{
  __shared__ float sm[3072];
  float* As = sm;            // [16][68] transposed
  float* Bs = sm + 16*68;    // [16][68]
  const int tid = threadIdx.x;
  const int twr = (MODE==1) ? blockIdx.y : 0;
  const int bnb = (MODE==1) ? 0 : blockIdx.y*64;
  const float* Bmt = (MODE==1) ? Bm + (size_t)twr*400*48 : Bm;
  const int bm = blockIdx.x*64;
  const int tx = tid & 15, ty = tid >> 4;
  const int arow = tid >> 2, akq = (tid & 3) * 4;
  const int bkr = tid >> 4, bn0 = (tid & 15) * 4;
  const int gr_a = bm + arow;
  constexpr int TJ = (MODE==1) ? 3 : 4;
  float hemask = 1.f;
  if(MODE==1) hemask = (gr_a < M && dgf[gr_a].x > 0.f) ? 1.f : 0.f;
  float acc[4][4] = {};
  for(int k0=0; k0<Kpad; k0+=16){
    float av[4];
    if(MODE==1){
      int k = k0 + akq;
      if(k < 320){
        if(gr_a < M){
          const unsigned short* Ag = (const unsigned short*)A0;
          uint2 p = *(const uint2*)&Ag[(size_t)gr_a*1600 + (size_t)twr*320 + k];
          av[0] = bf2f((unsigned short)(p.x & 0xFFFFu));
          av[1] = bf2f((unsigned short)(p.x >> 16));
          av[2] = bf2f((unsigned short)(p.y & 0xFFFFu));
          av[3] = bf2f((unsigned short)(p.y >> 16));
        } else { av[0]=av[1]=av[2]=av[3]=0.f; }
      } else {
        #pragma unroll
        for(int j=0;j<4;j++){
          int f = k + j - 320;
          av[j] = (gr_a < M && f < FI) ? A1[gr_a*FI + f] * hemask : 0.f;
        }
      }
    } else if(MODE==0){
      const float* Ah = (const float*)A0;
      #pragma unroll
      for(int j=0;j<4;j++){
        int k = k0 + akq + j;
        av[j] = (gr_a < M && k < FI) ? Ah[gr_a*FI + k] : 0.f;
      }
    } else {
      const float* Ah = (const float*)A0;
      #pragma unroll
      for(int j=0;j<4;j++){
        int k = k0 + akq + j;
        float vv = 0.f;
        if(gr_a < M){
          if(k < 75) vv = Ah[gr_a*75 + k];
          else if(k >= 80 && k < 155) vv = A1[gr_a*75 + (k-80)];
        }
        av[j] = vv;
      }
    }
    float4 bv = make_float4(0.f,0.f,0.f,0.f);
    if(bnb + bn0 < NB) bv = *(const float4*)&Bmt[(size_t)(k0+bkr)*NB + bnb + bn0];
    __syncthreads();
    #pragma unroll
    for(int j=0;j<4;j++) As[(akq+j)*68 + arow] = av[j];
    *(float4*)&Bs[bkr*68 + bn0] = bv;
    __syncthreads();
    #pragma unroll
    for(int kk=0;kk<16;kk++){
      float4 a4 = *(const float4*)&As[kk*68 + ty*4];
      float aa[4] = {a4.x,a4.y,a4.z,a4.w};
      float bb[TJ];
      #pragma unroll
      for(int j=0;j<TJ;j++) bb[j] = Bs[kk*68 + tx*TJ + j];
      #pragma unroll
      for(int i2=0;i2<4;i2++)
        #pragma unroll
        for(int j2=0;j2<TJ;j2++)
          acc[i2][j2] += aa[i2]*bb[j2];
    }
  }
  __syncthreads();
  if(MODE==1){
    #pragma unroll
    for(int i2=0;i2<4;i2++){
      #pragma unroll
      for(int j2=0;j2<3;j2++){
        int cc = tx*3 + j2;
        sm[(ty*4+i2)*48 + cc] = acc[i2][j2];
      }
    }
    __syncthreads();
    float* Cf = (float*)C;
    for(int idx=tid; idx<64*15; idx+=256){
      int r = idx / 15, o = idx - r*15;
      int gr = bm + r;
      if(gr < M){
        float4 dg = dgf[gr];
        float val = sm[r*48+o] + dg.z*sm[r*48+15+o] + dg.w*sm[r*48+30+o] + ex[twr*15 + o];
        Cf[(size_t)gr*75 + twr*15 + o] = val;
      }
    }
  } else if(MODE==0){
    unsigned short* Cv = (unsigned short*)C;
    #pragma unroll
    for(int i2=0;i2<4;i2++){
      int gr = bm + ty*4 + i2;
      if(gr >= M) continue;
      int gc0 = bnb + tx*4;
      if(gc0 < Ncols){
        unsigned lo = pk2(acc[i2][0], acc[i2][1]);
        unsigned hi = pk2(acc[i2][2], acc[i2][3]);
        *(uint2*)&Cv[(size_t)gr*400 + gc0] = make_uint2(lo,hi);
      }
    }
  } else {
    float* Cf = (float*)C;
    #pragma unroll
    for(int i2=0;i2<4;i2++){
      int gr = bm + ty*4 + i2;
      if(gr >= M) continue;
      #pragma unroll
      for(int j2=0;j2<4;j2++){
        int gc = bnb + tx*4 + j2;
        if(gc < Ncols){
          Cf[(size_t)gr*Ncols + gc] = acc[i2][j2] + ex[gc];
        }
      }
    }
  }
}

// ---------------------------------------------------------------- fused 5-tower aggregation
// 1 wave/node; 64 lanes cover the full 400-bf16 (200-uint) v row: lane slots u = lane + j*64
// (j=0..2 always, j=3 for lane<8). Slot u -> tower t=(2u)/80, feature f=(2u)%80 (f,f+1).
// agg layout: [n][tower][4 stats: mean|min|max|std][80] bf16  (row = 1600 bf16)
__global__ __launch_bounds__(256)
void k_aggf(const int* __restrict__ rowp, const unsigned int* __restrict__ edata,
            const float4* __restrict__ dgf, const unsigned short* __restrict__ v,
            const float* __restrict__ ctab_l, unsigned short* __restrict__ agg)
{
  __shared__ float cs[NT*4*80];
  int tid = threadIdx.x;
  for(int i=tid; i<NT*4*80; i+=256){
    int t = i/320, a = (i/80)%4, f = i%80;
    cs[i] = (f < FI) ? ctab_l[((size_t)(t*4+a))*FI + f] : 0.f;
  }
  __syncthreads();
  int wv = tid >> 6, lane = tid & 63;
  int n = blockIdx.x*4 + wv;
  if(n >= NN) return;
  int beg = rowp[n], end = rowp[n+1];
  bool has3 = lane < 8;
  int tj[4], fj[4];
  #pragma unroll
  for(int j=0;j<4;j++){
    int u = lane + j*64;
    if(u >= 200) u = 0;          // clamp inactive slot (lane>=8, j=3); never written back
    tj[j] = (2*u)/80; fj[j] = (2*u)%80;
  }
  float s0[4]={0,0,0,0}, s1[4]={0,0,0,0}, q0[4]={0,0,0,0}, q1[4]={0,0,0,0};
  float mn0[4], mn1[4], mx0[4], mx1[4];
  #pragma unroll
  for(int j=0;j<4;j++){ mn0[j]=3.4e38f; mn1[j]=3.4e38f; mx0[j]=-3.4e38f; mx1[j]=-3.4e38f; }
  for(int e=beg; e<end; e++){
    unsigned ed = edata[e];
    int src = (int)(ed & 0xFFFFu);
    int at  = (int)(ed >> 16);
    const unsigned* vr = (const unsigned*)(v + (size_t)src*400);
    unsigned p[4];
    p[0] = vr[lane];
    p[1] = vr[lane+64];
    p[2] = vr[lane+128];
    p[3] = has3 ? vr[lane+192] : 0u;
    int cb = at*80;
    #pragma unroll
    for(int j=0;j<4;j++){
      int ci = tj[j]*320 + cb + fj[j];
      float w0 = bf2f((unsigned short)(p[j] & 0xFFFFu)) + cs[ci];
      float w1 = bf2f((unsigned short)(p[j] >> 16))     + cs[ci+1];
      s0[j] += w0; q0[j] += w0*w0; mn0[j] = fminf(mn0[j],w0); mx0[j] = fmaxf(mx0[j],w0);
      s1[j] += w1; q1[j] += w1*w1; mn1[j] = fminf(mn1[j],w1); mx1[j] = fmaxf(mx1[j],w1);
    }
  }
  float4 dg = dgf[n];
  bool he = dg.x > 0.f;
  #pragma unroll
  for(int j=0;j<4;j++){
    if(j < 3 || has3){
      float m0 = s0[j]*dg.y, m1 = s1[j]*dg.y;
      float sd0 = sqrtf(fmaxf(q0[j]*dg.y - m0*m0, 0.f) + 1e-5f);
      float sd1 = sqrtf(fmaxf(q1[j]*dg.y - m1*m1, 0.f) + 1e-5f);
      float a0 = he ? mn0[j] : 0.f, a1 = he ? mn1[j] : 0.f;
      float b0 = he ? mx0[j] : 0.f, b1 = he ? mx1[j] : 0.f;
      unsigned short* o = agg + (size_t)n*1600 + (size_t)tj[j]*320;
      int f0 = fj[j];
      *(unsigned*)&o[      f0] = pk2(m0, m1);
      *(unsigned*)&o[ 80 + f0] = pk2(a0, a1);
      *(unsigned*)&o[160 + f0] = pk2(b0, b1);
      *(unsigned*)&o[240 + f0] = pk2(sd0, sd1);
    }
  }
}

// ---------------------------------------------------------------- batchnorm stats
__global__ void k_bnstat(const float* __restrict__ hc, float* __restrict__ bn){
  int f = threadIdx.x;
  if(f >= FI) return;
  float s=0.f, q=0.f;
  for(int n=blockIdx.x; n<NN; n+=gridDim.x){
    float xv = hc[(size_t)n*FI + f];
    s += xv; q += xv*xv;
  }
  atomicAdd(&bn[f], s);
  atomicAdd(&bn[FI+f], q);
}

// ---------------------------------------------------------------- batchnorm apply + relu
__global__ void k_bnapply(const float* __restrict__ hc, const float* __restrict__ bn,
                          const float* __restrict__ gam, const float* __restrict__ bet,
                          float* __restrict__ h){
  int i = blockIdx.x*256 + threadIdx.x;
  if(i >= NN*FI) return;
  int f = i % FI;
  float mu  = bn[f] * (1.f/NN);
  float var = bn[FI+f] * (1.f/NN) - mu*mu;
  float y = (hc[i] - mu) / sqrtf(var + 1e-5f) * gam[f] + bet[f];
  h[i] = fmaxf(y, 0.f);
}

// ---------------------------------------------------------------- graph pooling
__global__ void k_seg(const int* __restrict__ batch, const float* __restrict__ h,
                      float* __restrict__ g){
  __shared__ int slo, shi;
  int b = blockIdx.x, t = threadIdx.x;
  if(t==0) slo = lowerb(batch, NN, b);
  if(t==1) shi = lowerb(batch, NN, b+1);
  __syncthreads();
  if(t >= FI) return;
  float s = 0.f;
  for(int n=slo; n<shi; n++) s += h[(size_t)n*FI + t];
  g[b*FI + t] = s;
}

// ---------------------------------------------------------------- final MLP
__global__ void k_mlp(const float* __restrict__ g,
                      const float* __restrict__ w1, const float* __restrict__ b1,
                      const float* __restrict__ w2, const float* __restrict__ b2,
                      const float* __restrict__ w3, const float* __restrict__ b3,
                      float* __restrict__ out){
  __shared__ float gi[FI], l1[50], l2[25];
  int b = blockIdx.x, t = threadIdx.x;
  if(t < FI) gi[t] = g[b*FI + t];
  __syncthreads();
  if(t < 50){
    float s = b1[t];
    for(int f=0; f<FI; f++) s += gi[f]*w1[f*50 + t];
    l1[t] = fmaxf(s, 0.f);
  }
  __syncthreads();
  if(t < 25){
    float s = b2[t];
    for(int k=0; k<50; k++) s += l1[k]*w2[k*25 + t];
    l2[t] = fmaxf(s, 0.f);
  }
  __syncthreads();
  if(t == 0){
    float s = b3[0];
    for(int k=0; k<25; k++) s += l2[k]*w3[k];
    out[b] = s;
  }
}

// ================================================================ host
extern "C" void kernel_launch(void* const* d_in, const int* in_sizes, int n_in,
                              void* d_out, int out_size, void* d_ws, size_t ws_size,
                              hipStream_t stream)
{
  (void)in_sizes; (void)n_in; (void)out_size; (void)ws_size;
  const int*   X     = (const int*)d_in[0];
  const int*   EIDX  = (const int*)d_in[1];
  const int*   EATTR = (const int*)d_in[2];
  const int*   BATCH = (const int*)d_in[3];
  const float* NEMB  = (const float*)d_in[4];
  const float* EEMB  = (const float*)d_in[5];
  const float* ENCW  = (const float*)d_in[6];
  const float* ENCB  = (const float*)d_in[7];
  const float* PREW  = (const float*)d_in[8];
  const float* PREB  = (const float*)d_in[9];
  const float* POSTW = (const float*)d_in[10];
  const float* POSTB = (const float*)d_in[11];
  const float* LINW  = (const float*)d_in[12];
  const float* LINB  = (const float*)d_in[13];
  const float* GAM   = (const float*)d_in[14];
  const float* BET   = (const float*)d_in[15];
  const float* M1W   = (const float*)d_in[16];
  const float* M1B   = (const float*)d_in[17];
  const float* M2W   = (const float*)d_in[18];
  const float* M2B   = (const float*)d_in[19];
  const float* M3W   = (const float*)d_in[20];
  const float* M3B   = (const float*)d_in[21];
  float* OUT = (float*)d_out;

  char* base = (char*)d_ws; size_t off = 0;
  auto alloc = [&](size_t bytes)->void*{
    off = (off + 255) & ~(size_t)255;
    void* p = base + off; off += bytes; return p;
  };
  float*          h    = (float*)          alloc((size_t)NN*FI*4);
  float*          hc   = (float*)          alloc((size_t)NN*FI*4);
  float*          pbuf = (float*)          alloc((size_t)NN*FI*4);
  unsigned short* v    = (unsigned short*) alloc((size_t)NN*400*2);
  unsigned short* agg  = (unsigned short*) alloc((size_t)NN*1600*2);   // [n][tower][4][80]
  int*            rowp = (int*)            alloc((size_t)(NN+1)*4);
  int*            cnts = (int*)            alloc((size_t)NN*4);
  int*            bsum = (int*)            alloc((size_t)256*4);
  int*            boff = (int*)            alloc((size_t)256*4);
  float4*         dgf  = (float4*)         alloc((size_t)NN*16);
  unsigned*       edata= (unsigned*)       alloc((size_t)NE*4);
  float*          eenc = (float*)          alloc((size_t)NL*4*FI*4);
  float*          ctab = (float*)          alloc((size_t)NL*NT*4*FI*4);
  float*          BV   = (float*)          alloc((size_t)NL*80*400*4);
  float*          BP   = (float*)          alloc((size_t)NL*NT*400*48*4);
  float*          BX   = (float*)          alloc((size_t)NL*160*80*4);
  float*          bn   = (float*)          alloc((size_t)150*4);
  float*          gbuf = (float*)          alloc((size_t)NG*FI*4);

  hipMemsetAsync(cnts, 0, (size_t)NN*4, stream);
  k_embed  <<<cdiv(NN*FI,256),256,0,stream>>>(X, NEMB, h);
  k_count  <<<cdiv(NE,256),256,0,stream>>>(EIDX, cnts);
  k_bscan  <<<SCAN_NB,256,0,stream>>>(cnts, rowp, bsum);
  k_bsums  <<<1,256,0,stream>>>(bsum, boff, rowp);
  k_badd   <<<SCAN_NB,256,0,stream>>>(boff, cnts, rowp, dgf);
  hipMemsetAsync(cnts, 0, (size_t)NN*4, stream);
  k_scatter<<<cdiv(NE,256),256,0,stream>>>(EIDX, EATTR, rowp, cnts, edata);
  k_eenc   <<<cdiv(NL*4*FI,256),256,0,stream>>>(EEMB, ENCW, ENCB, eenc);
  k_ctab   <<<cdiv(NL*NT*4*FI,256),256,0,stream>>>(eenc, PREW, PREB, ctab);
  k_bv     <<<cdiv(NL*80*400,256),256,0,stream>>>(PREW, BV);
  k_bpost  <<<cdiv(NL*NT*400*48,256),256,0,stream>>>(POSTW, PREW, BP);
  k_bx     <<<cdiv(NL*160*80,256),256,0,stream>>>(POSTW, LINW, BX);

  for(int l=0; l<NL; l++){
    k_gemm<0><<<dim3(cdiv(NN,64),7),256,0,stream>>>(
        h, nullptr, BV + (size_t)l*80*400, nullptr, dgf, v, NN, 80, 400, 400, 0);
    k_aggf<<<cdiv(NN,4),256,0,stream>>>(
        rowp, edata, dgf, v, ctab + (size_t)l*NT*4*FI, agg);
    k_gemm<1><<<dim3(cdiv(NN,64),NT),256,0,stream>>>(
        agg, h, BP + (size_t)l*NT*400*48, POSTB + (size_t)l*NT*15, dgf, pbuf,
        NN, 400, 48, 75, 0);
    k_gemm<2><<<dim3(cdiv(NN,64),2),256,0,stream>>>(
        h, pbuf, BX + (size_t)l*160*80, LINB + l*FI, dgf, hc, NN, 160, 80, 75, 0);
    hipMemsetAsync(bn, 0, 150*4, stream);
    k_bnstat <<<256,128,0,stream>>>(hc, bn);
    k_bnapply<<<cdiv(NN*FI,256),256,0,stream>>>(hc, bn, GAM + l*FI, BET + l*FI, h);
  }
  k_seg<<<NG,128,0,stream>>>(BATCH, h, gbuf);
  k_mlp<<<NG,128,0,stream>>>(gbuf, M1W, M1B, M2W, M2B, M3W, M3B, OUT);
}